// Round 7
// baseline (276.614 us; speedup 1.0000x reference)
//
#include <hip/hip_runtime.h>

#define DIM 256
// combined layout: per node 3 slots (x, oh, th), each 256 bf16 = 512 B
// node stride: 1536 B = 192 uint2 = 96 uint4
#define NODE_U2 192
#define NODE_U4 96
#define SLOT_OH_U2 64
#define SLOT_TH_U2 128
#define SLOT_OH_U4 32
#define SLOT_TH_U4 64

// col-block bucketing: 16 buckets of 4096 nodes (2MB src slice per bucket)
#define CB_SHIFT 12
#define CB 16

// ---- bf16 helpers (manual, RNE pack / exact unpack) -----------------------
__device__ __forceinline__ unsigned int f2bf_rne(float f) {
    unsigned int u = __float_as_uint(f);
    return (u + 0x7fffu + ((u >> 16) & 1u)) >> 16;
}
__device__ __forceinline__ float bf_lo(unsigned int u) {
    return __uint_as_float(u << 16);
}
__device__ __forceinline__ float bf_hi(unsigned int u) {
    return __uint_as_float(u & 0xffff0000u);
}
__device__ __forceinline__ unsigned int pack2(float a, float b) {
    return f2bf_rne(a) | (f2bf_rne(b) << 16);
}

#define ACC8(v)                                            \
    do {                                                   \
        a0 += bf_lo((v).x); a1 += bf_hi((v).x);            \
        a2 += bf_lo((v).y); a3 += bf_hi((v).y);            \
        a4 += bf_lo((v).z); a5 += bf_hi((v).z);            \
        a6 += bf_lo((v).w); a7 += bf_hi((v).w);            \
    } while (0)

// ---------------------------------------------------------------------------
// 1) fused: combined[node][slot x] = bf16(nv * w)  AND  2D histogram
//    cnt2[row*CB + (col>>CB_SHIFT)]++
// ---------------------------------------------------------------------------
__global__ void x_and_hist_kernel(const float* __restrict__ nv,
                                  const float* __restrict__ w,
                                  uint2* __restrict__ cmb,
                                  int total_u2,
                                  const int* __restrict__ adj_row,
                                  const int* __restrict__ adj_col,
                                  int* __restrict__ cnt2, int E) {
    int i0 = blockIdx.x * blockDim.x + threadIdx.x;
    int stride = gridDim.x * blockDim.x;
    for (int i = i0; i < total_u2; i += stride) {
        float4 v = reinterpret_cast<const float4*>(nv)[i];
        int node = i >> 6;
        int j = i & 63;
        float wt = w[node];
        uint2 r;
        r.x = pack2(v.x * wt, v.y * wt);
        r.y = pack2(v.z * wt, v.w * wt);
        cmb[(size_t)node * NODE_U2 + j] = r;
    }
    for (int e = i0; e < E; e += stride) {
        int key = adj_row[e] * CB + (adj_col[e] >> CB_SHIFT);
        atomicAdd(&cnt2[key], 1);
    }
}

// ---------------------------------------------------------------------------
// scan hierarchy (generic)
// ---------------------------------------------------------------------------
__global__ void block_sum_kernel(const int* __restrict__ in,
                                 int* __restrict__ sums, int n) {
    __shared__ int lds[256];
    int i = blockIdx.x * 256 + threadIdx.x;
    lds[threadIdx.x] = (i < n) ? in[i] : 0;
    __syncthreads();
    #pragma unroll
    for (int off = 128; off > 0; off >>= 1) {
        if (threadIdx.x < off) lds[threadIdx.x] += lds[threadIdx.x + off];
        __syncthreads();
    }
    if (threadIdx.x == 0) sums[blockIdx.x] = lds[0];
}

// single block: exclusive-scan sums[0..nb) in place; write total to *total_out
__global__ void scan_sums_kernel(int* __restrict__ sums, int nb,
                                 int* __restrict__ total_out) {
    __shared__ int lds[256];
    int v = (threadIdx.x < nb) ? sums[threadIdx.x] : 0;
    lds[threadIdx.x] = v;
    __syncthreads();
    #pragma unroll
    for (int off = 1; off < 256; off <<= 1) {
        int t = (threadIdx.x >= off) ? lds[threadIdx.x - off] : 0;
        __syncthreads();
        lds[threadIdx.x] += t;
        __syncthreads();
    }
    if (threadIdx.x < nb) sums[threadIdx.x] = lds[threadIdx.x] - v;
    if (threadIdx.x == 255) *total_out = lds[255];
}

// per-block exclusive scan + scanned-block-sum offset; writes two copies
// (pass the same pointer twice if only one is needed; in==out1 is safe)
__global__ void scan_block_kernel(const int* __restrict__ in,
                                  const int* __restrict__ sums,
                                  int* __restrict__ out1,
                                  int* __restrict__ out2, int n) {
    __shared__ int lds[256];
    int i = blockIdx.x * 256 + threadIdx.x;
    int v = (i < n) ? in[i] : 0;
    lds[threadIdx.x] = v;
    __syncthreads();
    #pragma unroll
    for (int off = 1; off < 256; off <<= 1) {
        int t = (threadIdx.x >= off) ? lds[threadIdx.x - off] : 0;
        __syncthreads();
        lds[threadIdx.x] += t;
        __syncthreads();
    }
    if (i < n) {
        int excl = sums[blockIdx.x] + lds[threadIdx.x] - v;
        out1[i] = excl;
        out2[i] = excl;
    }
}

// row_ptr[r] = cur2[r*CB]  (row boundary = start of its bucket 0)
__global__ void extract_rowptr_kernel(const int* __restrict__ cur2,
                                      int* __restrict__ row_ptr, int n) {
    int i = blockIdx.x * blockDim.x + threadIdx.x;
    if (i < n) row_ptr[i] = cur2[(size_t)i * CB];
}

// perm[cursor2[row*CB + colblk]++] = col
__global__ void scatter_perm_kernel(const int* __restrict__ row,
                                    const int* __restrict__ col,
                                    int* __restrict__ cursor2,
                                    int* __restrict__ perm, int nedges) {
    int e = blockIdx.x * blockDim.x + threadIdx.x;
    if (e < nedges) {
        int c = col[e];
        int key = row[e] * CB + (c >> CB_SHIFT);
        int pos = atomicAdd(&cursor2[key], 1);
        perm[pos] = c;
    }
}

// ---------------------------------------------------------------------------
// Gather segment-sum, one wave per row. Lanes 0-31 walk edges beg,beg+2,...,
// lanes 32-63 walk beg+1,beg+3,...  4 edges per half in flight.
// Edges within a row are bucketed by col-block -> concurrent waves read a
// 2MB-resident slice of src (L2 phase locality).
// ---------------------------------------------------------------------------
__global__ void gather_hop_kernel(const int* __restrict__ row_ptr,
                                  const int* __restrict__ perm,
                                  const uint4* __restrict__ src,
                                  uint4* __restrict__ dst, int n) {
    int gid = blockIdx.x * blockDim.x + threadIdx.x;
    int r = gid >> 6;
    if (r >= n) return;
    int lane = gid & 63;
    int h = lane >> 5;      // which half-wave
    int l = lane & 31;      // uint4 index within row

    int beg = row_ptr[r];
    int end = row_ptr[r + 1];

    float a0 = 0.f, a1 = 0.f, a2 = 0.f, a3 = 0.f;
    float a4 = 0.f, a5 = 0.f, a6 = 0.f, a7 = 0.f;

    int e = beg + h;
    while (e + 6 < end) {
        int c0 = perm[e];
        int c1 = perm[e + 2];
        int c2 = perm[e + 4];
        int c3 = perm[e + 6];
        uint4 v0 = src[(size_t)c0 * NODE_U4 + l];
        uint4 v1 = src[(size_t)c1 * NODE_U4 + l];
        uint4 v2 = src[(size_t)c2 * NODE_U4 + l];
        uint4 v3 = src[(size_t)c3 * NODE_U4 + l];
        ACC8(v0); ACC8(v1); ACC8(v2); ACC8(v3);
        e += 8;
    }
    while (e < end) {
        int c0 = perm[e];
        uint4 v0 = src[(size_t)c0 * NODE_U4 + l];
        ACC8(v0);
        e += 2;
    }

    // combine halves
    a0 += __shfl_xor(a0, 32); a1 += __shfl_xor(a1, 32);
    a2 += __shfl_xor(a2, 32); a3 += __shfl_xor(a3, 32);
    a4 += __shfl_xor(a4, 32); a5 += __shfl_xor(a5, 32);
    a6 += __shfl_xor(a6, 32); a7 += __shfl_xor(a7, 32);

    if (lane < 32) {
        uint4 o;
        o.x = pack2(a0, a1);
        o.y = pack2(a2, a3);
        o.z = pack2(a4, a5);
        o.w = pack2(a6, a7);
        dst[(size_t)r * NODE_U4 + l] = o;
    }
}

// ---------------------------------------------------------------------------
// Query: 32 lanes per query (uint4 loads), 2 queries per wave.
// ---------------------------------------------------------------------------
__global__ void query_kernel(const int* __restrict__ es,
                             const int* __restrict__ et,
                             const uint4* __restrict__ cmb4,
                             const int* __restrict__ row_ptr,
                             float* __restrict__ out, int nq) {
    int gid = blockIdx.x * blockDim.x + threadIdx.x;
    int q = gid >> 5;
    if (q >= nq) return;
    int l = gid & 31;

    int s = es[q];
    int t = et[q];

    const uint4* ns = cmb4 + (size_t)s * NODE_U4;
    const uint4* nt = cmb4 + (size_t)t * NODE_U4;

    uint4 vxs = ns[l];
    uint4 vos = ns[SLOT_OH_U4 + l];
    uint4 vts = ns[SLOT_TH_U4 + l];
    uint4 vxt = nt[l];
    uint4 vot = nt[SLOT_OH_U4 + l];
    uint4 vtt = nt[SLOT_TH_U4 + l];
    float ds = (float)(row_ptr[s + 1] - row_ptr[s]);
    float dt = (float)(row_ptr[t + 1] - row_ptr[t]);

    float c11 = 0.f, c12 = 0.f, c22 = 0.f, cs = 0.f;
    const unsigned int* pxs = (const unsigned int*)&vxs;
    const unsigned int* pxt = (const unsigned int*)&vxt;
    const unsigned int* pos_ = (const unsigned int*)&vos;
    const unsigned int* pot = (const unsigned int*)&vot;
    const unsigned int* pts = (const unsigned int*)&vts;
    const unsigned int* ptt = (const unsigned int*)&vtt;
    #pragma unroll
    for (int k = 0; k < 4; ++k) {
        {
            float fxs = bf_lo(pxs[k]), fxt = bf_lo(pxt[k]);
            float fos = bf_lo(pos_[k]), fot = bf_lo(pot[k]);
            float fts = bf_lo(pts[k]), ftt = bf_lo(ptt[k]);
            c11 += fos * fot;
            c12 += fos * ftt + fts * fot;
            float as = fts - ds * fxs;
            float bt = ftt - dt * fxt;
            c22 += as * bt;
            cs  += fos * fts + fot * ftt;
        }
        {
            float fxs = bf_hi(pxs[k]), fxt = bf_hi(pxt[k]);
            float fos = bf_hi(pos_[k]), fot = bf_hi(pot[k]);
            float fts = bf_hi(pts[k]), ftt = bf_hi(ptt[k]);
            c11 += fos * fot;
            c12 += fos * ftt + fts * fot;
            float as = fts - ds * fxs;
            float bt = ftt - dt * fxt;
            c22 += as * bt;
            cs  += fos * fts + fot * ftt;
        }
    }

    #pragma unroll
    for (int off = 16; off > 0; off >>= 1) {
        c11 += __shfl_xor(c11, off);
        c12 += __shfl_xor(c12, off);
        c22 += __shfl_xor(c22, off);
        cs  += __shfl_xor(cs,  off);
    }

    if (l == 0) {
        out[q]          = c11;
        out[nq + q]     = c12;
        out[2 * nq + q] = c22;
        out[3 * nq + q] = cs;
    }
}

// ---------------------------------------------------------------------------
extern "C" void kernel_launch(void* const* d_in, const int* in_sizes, int n_in,
                              void* d_out, int out_size, void* d_ws, size_t ws_size,
                              hipStream_t stream) {
    const int*   edges        = (const int*)  d_in[0];  // [2, EQ]
    const int*   adj_row      = (const int*)  d_in[1];  // [E]
    const int*   adj_col      = (const int*)  d_in[2];  // [E]
    const float* node_weight  = (const float*)d_in[3];  // [N]
    const float* node_vectors = (const float*)d_in[4];  // [N, DIM]

    const int EQ = in_sizes[0] / 2;
    const int E  = in_sizes[1];
    const int N  = in_sizes[3];

    // workspace: combined bf16 [N][3][256] then CSR arrays
    uint2* cmb = (uint2*)d_ws;                          // N * 192 uint2 = 76.8 MB
    int* row_ptr = (int*)(cmb + (size_t)N * NODE_U2);   // [N+1]
    int* cnt2    = row_ptr + (N + 1);                   // [N*CB]
    int* cur2    = cnt2 + (size_t)N * CB;               // [N*CB] pristine excl
    int* cursor2 = cur2 + (size_t)N * CB;               // [N*CB] mutable
    int* perm    = cursor2 + (size_t)N * CB;            // [E]
    int* s1      = perm + E;                            // [ceil(N*CB/256)]
    int* s2      = s1 + ((size_t)N * CB + 255) / 256 + 8; // [<=256]

    const int* es = edges;
    const int* et = edges + EQ;
    float* out = (float*)d_out;

    const int n0  = N * CB;                 // 800000
    const int nb0 = (n0 + 255) / 256;       // 3125
    const int nb1 = (nb0 + 255) / 256;      // 13

    // --- fused x + 2D histogram ---
    hipMemsetAsync(cnt2, 0, (size_t)n0 * sizeof(int), stream);
    int total_u2 = N * 64;
    x_and_hist_kernel<<<2048, 256, 0, stream>>>(node_vectors, node_weight, cmb,
                                                total_u2, adj_row, adj_col,
                                                cnt2, E);

    // --- 3-level exclusive scan of cnt2 -> cur2 (+cursor2 copy) ---
    block_sum_kernel<<<nb0, 256, 0, stream>>>(cnt2, s1, n0);
    block_sum_kernel<<<nb1, 256, 0, stream>>>(s1, s2, nb0);
    scan_sums_kernel<<<1, 256, 0, stream>>>(s2, nb1, row_ptr + N);  // total=E
    scan_block_kernel<<<nb1, 256, 0, stream>>>(s1, s2, s1, s1, nb0); // in-place
    scan_block_kernel<<<nb0, 256, 0, stream>>>(cnt2, s1, cur2, cursor2, n0);
    extract_rowptr_kernel<<<(N + 255) / 256, 256, 0, stream>>>(cur2, row_ptr, N);

    // --- bucketed permutation ---
    scatter_perm_kernel<<<(E + 255) / 256, 256, 0, stream>>>(adj_row, adj_col,
                                                             cursor2, perm, E);

    // --- one_hop / two_hop via gather (col-block phase-local) ---
    const uint4* cmb4 = (const uint4*)cmb;
    int gthreads = N * 64;
    int gblocks = (gthreads + 255) / 256;
    gather_hop_kernel<<<gblocks, 256, 0, stream>>>(
        row_ptr, perm, cmb4, (uint4*)cmb4 + SLOT_OH_U4, N);
    gather_hop_kernel<<<gblocks, 256, 0, stream>>>(
        row_ptr, perm, cmb4 + SLOT_OH_U4, (uint4*)cmb4 + SLOT_TH_U4, N);

    // --- queries ---
    int qthreads = EQ * 32;
    query_kernel<<<(qthreads + 255) / 256, 256, 0, stream>>>(
        es, et, cmb4, row_ptr, out, EQ);
}

// Round 8
// 256.391 us; speedup vs baseline: 1.0789x; 1.0789x over previous
//
#include <hip/hip_runtime.h>

#define DIM 256
// contiguous combined layout (query path): per node 3 slots (x, oh, th),
// each 256 bf16 = 512 B; node stride 1536 B = 192 uint2 = 96 uint4
#define NODE_U2 192
#define NODE_U4 96
#define SLOT_OH_U2 64
#define SLOT_TH_U2 128
#define SLOT_OH_U4 32
#define SLOT_TH_U4 64

// dimension slicing (gather path): 8 slices x 32 dims (64 B = 4 uint4)
#define NSL 8

// ---- bf16 helpers (manual, RNE pack / exact unpack) -----------------------
__device__ __forceinline__ unsigned int f2bf_rne(float f) {
    unsigned int u = __float_as_uint(f);
    return (u + 0x7fffu + ((u >> 16) & 1u)) >> 16;
}
__device__ __forceinline__ float bf_lo(unsigned int u) {
    return __uint_as_float(u << 16);
}
__device__ __forceinline__ float bf_hi(unsigned int u) {
    return __uint_as_float(u & 0xffff0000u);
}
__device__ __forceinline__ unsigned int pack2(float a, float b) {
    return f2bf_rne(a) | (f2bf_rne(b) << 16);
}

#define ACC8(v)                                            \
    do {                                                   \
        a0 += bf_lo((v).x); a1 += bf_hi((v).x);            \
        a2 += bf_lo((v).y); a3 += bf_hi((v).y);            \
        a4 += bf_lo((v).z); a5 += bf_hi((v).z);            \
        a6 += bf_lo((v).w); a7 += bf_hi((v).w);            \
    } while (0)

// ---------------------------------------------------------------------------
// 1) fused: x slot (contiguous) + x sliced + 1D histogram of adj_row
// ---------------------------------------------------------------------------
__global__ void x_and_hist_kernel(const float* __restrict__ nv,
                                  const float* __restrict__ w,
                                  uint2* __restrict__ cmb,
                                  uint2* __restrict__ xs_sl,
                                  int total_u2, int N,
                                  const int* __restrict__ adj_row,
                                  int* __restrict__ cnt, int E) {
    int i0 = blockIdx.x * blockDim.x + threadIdx.x;
    int stride = gridDim.x * blockDim.x;
    for (int i = i0; i < total_u2; i += stride) {
        float4 v = reinterpret_cast<const float4*>(nv)[i];
        int node = i >> 6;          // 64 uint2 per row
        int j = i & 63;             // uint2 index in row (4 dims)
        float wt = w[node];
        uint2 r;
        r.x = pack2(v.x * wt, v.y * wt);
        r.y = pack2(v.z * wt, v.w * wt);
        cmb[(size_t)node * NODE_U2 + j] = r;
        int s = j >> 3;             // slice = dims/32
        xs_sl[((size_t)s * N + node) * 8 + (j & 7)] = r;
    }
    for (int e = i0; e < E; e += stride) {
        atomicAdd(&cnt[adj_row[e]], 1);
    }
}

// ---------------------------------------------------------------------------
// CSR build (2-level scan; nb0 = ceil(N/256) = 196 <= 256)
// ---------------------------------------------------------------------------
__global__ void block_sum_kernel(const int* __restrict__ in,
                                 int* __restrict__ sums, int n) {
    __shared__ int lds[256];
    int i = blockIdx.x * 256 + threadIdx.x;
    lds[threadIdx.x] = (i < n) ? in[i] : 0;
    __syncthreads();
    #pragma unroll
    for (int off = 128; off > 0; off >>= 1) {
        if (threadIdx.x < off) lds[threadIdx.x] += lds[threadIdx.x + off];
        __syncthreads();
    }
    if (threadIdx.x == 0) sums[blockIdx.x] = lds[0];
}

__global__ void scan_sums_kernel(int* __restrict__ sums, int nb,
                                 int* __restrict__ total_out) {
    __shared__ int lds[256];
    int v = (threadIdx.x < nb) ? sums[threadIdx.x] : 0;
    lds[threadIdx.x] = v;
    __syncthreads();
    #pragma unroll
    for (int off = 1; off < 256; off <<= 1) {
        int t = (threadIdx.x >= off) ? lds[threadIdx.x - off] : 0;
        __syncthreads();
        lds[threadIdx.x] += t;
        __syncthreads();
    }
    if (threadIdx.x < nb) sums[threadIdx.x] = lds[threadIdx.x] - v;
    if (threadIdx.x == 255) *total_out = lds[255];
}

__global__ void scan_block_kernel(const int* __restrict__ in,
                                  const int* __restrict__ sums,
                                  int* __restrict__ out1,
                                  int* __restrict__ out2, int n) {
    __shared__ int lds[256];
    int i = blockIdx.x * 256 + threadIdx.x;
    int v = (i < n) ? in[i] : 0;
    lds[threadIdx.x] = v;
    __syncthreads();
    #pragma unroll
    for (int off = 1; off < 256; off <<= 1) {
        int t = (threadIdx.x >= off) ? lds[threadIdx.x - off] : 0;
        __syncthreads();
        lds[threadIdx.x] += t;
        __syncthreads();
    }
    if (i < n) {
        int excl = sums[blockIdx.x] + lds[threadIdx.x] - v;
        out1[i] = excl;
        out2[i] = excl;
    }
}

__global__ void scatter_perm_kernel(const int* __restrict__ row,
                                    const int* __restrict__ col,
                                    int* __restrict__ cursor,
                                    int* __restrict__ perm, int nedges) {
    int e = blockIdx.x * blockDim.x + threadIdx.x;
    if (e < nedges) {
        int pos = atomicAdd(&cursor[row[e]], 1);
        perm[pos] = col[e];
    }
}

// ---------------------------------------------------------------------------
// Dimension-sliced gather: slice s = blockIdx % 8 (XCD-pinned); block handles
// 64 rows of slice s; 4 lanes per row each load one uint4 (16B) of the 64B
// sliced row. src slab per slice = 3.2MB -> L2-resident on its XCD.
// Writes sliced copy (if dst_sl) + contiguous slot copy (for query).
// ---------------------------------------------------------------------------
__global__ void gather_sliced_kernel(const int* __restrict__ row_ptr,
                                     const int* __restrict__ perm,
                                     const uint4* __restrict__ src_sl,
                                     uint4* __restrict__ dst_sl,
                                     uint4* __restrict__ dst_cmb_slot,
                                     int N) {
    int s = blockIdx.x & (NSL - 1);
    int rb = blockIdx.x >> 3;
    int g = threadIdx.x >> 2;       // row group 0..63
    int j = threadIdx.x & 3;        // uint4 within 64B
    int r = rb * 64 + g;
    if (r >= N) return;

    int beg = row_ptr[r];
    int end = row_ptr[r + 1];

    const uint4* base = src_sl + (size_t)s * N * 4;

    float a0 = 0.f, a1 = 0.f, a2 = 0.f, a3 = 0.f;
    float a4 = 0.f, a5 = 0.f, a6 = 0.f, a7 = 0.f;

    int e = beg;
    for (; e + 3 < end; e += 4) {
        int c0 = perm[e];
        int c1 = perm[e + 1];
        int c2 = perm[e + 2];
        int c3 = perm[e + 3];
        uint4 v0 = base[(size_t)c0 * 4 + j];
        uint4 v1 = base[(size_t)c1 * 4 + j];
        uint4 v2 = base[(size_t)c2 * 4 + j];
        uint4 v3 = base[(size_t)c3 * 4 + j];
        ACC8(v0); ACC8(v1); ACC8(v2); ACC8(v3);
    }
    for (; e < end; ++e) {
        int c = perm[e];
        uint4 v = base[(size_t)c * 4 + j];
        ACC8(v);
    }

    uint4 o;
    o.x = pack2(a0, a1);
    o.y = pack2(a2, a3);
    o.z = pack2(a4, a5);
    o.w = pack2(a6, a7);
    if (dst_sl) dst_sl[((size_t)s * N + r) * 4 + j] = o;
    dst_cmb_slot[(size_t)r * NODE_U4 + s * 4 + j] = o;
}

// ---------------------------------------------------------------------------
// Query: 32 lanes per query (uint4 loads), 2 queries per wave (contiguous cmb)
// ---------------------------------------------------------------------------
__global__ void query_kernel(const int* __restrict__ es,
                             const int* __restrict__ et,
                             const uint4* __restrict__ cmb4,
                             const int* __restrict__ row_ptr,
                             float* __restrict__ out, int nq) {
    int gid = blockIdx.x * blockDim.x + threadIdx.x;
    int q = gid >> 5;
    if (q >= nq) return;
    int l = gid & 31;

    int s = es[q];
    int t = et[q];

    const uint4* ns = cmb4 + (size_t)s * NODE_U4;
    const uint4* nt = cmb4 + (size_t)t * NODE_U4;

    uint4 vxs = ns[l];
    uint4 vos = ns[SLOT_OH_U4 + l];
    uint4 vts = ns[SLOT_TH_U4 + l];
    uint4 vxt = nt[l];
    uint4 vot = nt[SLOT_OH_U4 + l];
    uint4 vtt = nt[SLOT_TH_U4 + l];
    float ds = (float)(row_ptr[s + 1] - row_ptr[s]);
    float dt = (float)(row_ptr[t + 1] - row_ptr[t]);

    float c11 = 0.f, c12 = 0.f, c22 = 0.f, cs = 0.f;
    const unsigned int* pxs = (const unsigned int*)&vxs;
    const unsigned int* pxt = (const unsigned int*)&vxt;
    const unsigned int* pos_ = (const unsigned int*)&vos;
    const unsigned int* pot = (const unsigned int*)&vot;
    const unsigned int* pts = (const unsigned int*)&vts;
    const unsigned int* ptt = (const unsigned int*)&vtt;
    #pragma unroll
    for (int k = 0; k < 4; ++k) {
        {
            float fxs = bf_lo(pxs[k]), fxt = bf_lo(pxt[k]);
            float fos = bf_lo(pos_[k]), fot = bf_lo(pot[k]);
            float fts = bf_lo(pts[k]), ftt = bf_lo(ptt[k]);
            c11 += fos * fot;
            c12 += fos * ftt + fts * fot;
            float as = fts - ds * fxs;
            float bt = ftt - dt * fxt;
            c22 += as * bt;
            cs  += fos * fts + fot * ftt;
        }
        {
            float fxs = bf_hi(pxs[k]), fxt = bf_hi(pxt[k]);
            float fos = bf_hi(pos_[k]), fot = bf_hi(pot[k]);
            float fts = bf_hi(pts[k]), ftt = bf_hi(ptt[k]);
            c11 += fos * fot;
            c12 += fos * ftt + fts * fot;
            float as = fts - ds * fxs;
            float bt = ftt - dt * fxt;
            c22 += as * bt;
            cs  += fos * fts + fot * ftt;
        }
    }

    #pragma unroll
    for (int off = 16; off > 0; off >>= 1) {
        c11 += __shfl_xor(c11, off);
        c12 += __shfl_xor(c12, off);
        c22 += __shfl_xor(c22, off);
        cs  += __shfl_xor(cs,  off);
    }

    if (l == 0) {
        out[q]          = c11;
        out[nq + q]     = c12;
        out[2 * nq + q] = c22;
        out[3 * nq + q] = cs;
    }
}

// ---------------------------------------------------------------------------
extern "C" void kernel_launch(void* const* d_in, const int* in_sizes, int n_in,
                              void* d_out, int out_size, void* d_ws, size_t ws_size,
                              hipStream_t stream) {
    const int*   edges        = (const int*)  d_in[0];  // [2, EQ]
    const int*   adj_row      = (const int*)  d_in[1];  // [E]
    const int*   adj_col      = (const int*)  d_in[2];  // [E]
    const float* node_weight  = (const float*)d_in[3];  // [N]
    const float* node_vectors = (const float*)d_in[4];  // [N, DIM]

    const int EQ = in_sizes[0] / 2;
    const int E  = in_sizes[1];
    const int N  = in_sizes[3];

    // workspace layout
    uint2* cmb   = (uint2*)d_ws;                        // 76.8 MB contiguous
    uint2* xs_sl = cmb + (size_t)N * NODE_U2;           // 25.6 MB sliced x
    uint2* oh_sl = xs_sl + (size_t)N * NSL * 8;         // 25.6 MB sliced oh
    int* row_ptr = (int*)(oh_sl + (size_t)N * NSL * 8); // [N+1]
    int* cursor  = row_ptr + (N + 1);                   // [N]
    int* cnt     = cursor + N;                          // [N]
    int* perm    = cnt + N;                             // [E]
    int* s1      = perm + E;                            // [ceil(N/256)]

    const int* es = edges;
    const int* et = edges + EQ;
    float* out = (float*)d_out;

    const int nb0 = (N + 255) / 256;   // 196

    // --- fused x (both layouts) + histogram ---
    hipMemsetAsync(cnt, 0, (size_t)N * sizeof(int), stream);
    int total_u2 = N * 64;
    x_and_hist_kernel<<<2048, 256, 0, stream>>>(node_vectors, node_weight,
                                                cmb, xs_sl, total_u2, N,
                                                adj_row, cnt, E);

    // --- CSR scan + permutation ---
    block_sum_kernel<<<nb0, 256, 0, stream>>>(cnt, s1, N);
    scan_sums_kernel<<<1, 256, 0, stream>>>(s1, nb0, row_ptr + N);
    scan_block_kernel<<<nb0, 256, 0, stream>>>(cnt, s1, row_ptr, cursor, N);
    scatter_perm_kernel<<<(E + 255) / 256, 256, 0, stream>>>(adj_row, adj_col,
                                                             cursor, perm, E);

    // --- one_hop / two_hop via XCD-pinned sliced gather ---
    const uint4* xs4 = (const uint4*)xs_sl;
    uint4* oh4 = (uint4*)oh_sl;
    uint4* cmb4 = (uint4*)cmb;
    int nrb = (N + 63) / 64;           // 782 row-blocks
    int gblocks = nrb * NSL;           // 6256
    gather_sliced_kernel<<<gblocks, 256, 0, stream>>>(
        row_ptr, perm, xs4, oh4, cmb4 + SLOT_OH_U4, N);
    gather_sliced_kernel<<<gblocks, 256, 0, stream>>>(
        row_ptr, perm, (const uint4*)oh4, (uint4*)nullptr,
        cmb4 + SLOT_TH_U4, N);

    // --- queries ---
    int qthreads = EQ * 32;
    query_kernel<<<(qthreads + 255) / 256, 256, 0, stream>>>(
        es, et, cmb4, row_ptr, out, EQ);
}

// Round 9
// 232.449 us; speedup vs baseline: 1.1900x; 1.1030x over previous
//
#include <hip/hip_runtime.h>

#define DIM 256
// contiguous combined layout (query path): per node 3 slots (x, oh, th),
// each 256 bf16 = 512 B; node stride 1536 B = 192 uint2 = 96 uint4
#define NODE_U2 192
#define NODE_U4 96
#define SLOT_OH_U4 32
#define SLOT_TH_U4 64

// dimension slicing (gather path): 8 slices x 32 dims (64 B = 4 uint4)
#define NSL 8
// LDS edge-stage capacity (64 rows * mean 16 = 1024, 2048 = +32 sigma)
#define ECAP 2048

// ---- bf16 helpers (manual, RNE pack / exact unpack) -----------------------
__device__ __forceinline__ unsigned int f2bf_rne(float f) {
    unsigned int u = __float_as_uint(f);
    return (u + 0x7fffu + ((u >> 16) & 1u)) >> 16;
}
__device__ __forceinline__ float bf_lo(unsigned int u) {
    return __uint_as_float(u << 16);
}
__device__ __forceinline__ float bf_hi(unsigned int u) {
    return __uint_as_float(u & 0xffff0000u);
}
__device__ __forceinline__ unsigned int pack2(float a, float b) {
    return f2bf_rne(a) | (f2bf_rne(b) << 16);
}

#define ACC8(v)                                            \
    do {                                                   \
        a0 += bf_lo((v).x); a1 += bf_hi((v).x);            \
        a2 += bf_lo((v).y); a3 += bf_hi((v).y);            \
        a4 += bf_lo((v).z); a5 += bf_hi((v).z);            \
        a6 += bf_lo((v).w); a7 += bf_hi((v).w);            \
    } while (0)

// ---------------------------------------------------------------------------
// 1) fused: x slot (contiguous) + x sliced + XCD-partitioned histogram
// ---------------------------------------------------------------------------
__global__ void x_and_hist_kernel(const float* __restrict__ nv,
                                  const float* __restrict__ w,
                                  uint2* __restrict__ cmb,
                                  uint2* __restrict__ xs_sl,
                                  int total_u2, int N,
                                  const int* __restrict__ adj_row,
                                  int* __restrict__ cnt, int E, int per_part) {
    int i0 = blockIdx.x * blockDim.x + threadIdx.x;
    int stride = gridDim.x * blockDim.x;
    for (int i = i0; i < total_u2; i += stride) {
        float4 v = reinterpret_cast<const float4*>(nv)[i];
        int node = i >> 6;          // 64 uint2 per row
        int j = i & 63;             // uint2 index in row (4 dims)
        float wt = w[node];
        uint2 r;
        r.x = pack2(v.x * wt, v.y * wt);
        r.y = pack2(v.z * wt, v.w * wt);
        cmb[(size_t)node * NODE_U2 + j] = r;
        int s = j >> 3;             // slice = dims/32
        xs_sl[((size_t)s * N + node) * 8 + (j & 7)] = r;
    }
    // histogram, XCD-partitioned by row range (atomics stay in one L2)
    int bp = blockIdx.x & 7;
    unsigned lo = (unsigned)(bp * per_part);
    int chunk = blockIdx.x >> 3;
    int nchunks = gridDim.x >> 3;
    int E4 = E >> 2;
    for (int i = chunk * 256 + threadIdx.x; i < E4; i += nchunks * 256) {
        int4 r4 = reinterpret_cast<const int4*>(adj_row)[i];
        if ((unsigned)(r4.x - lo) < (unsigned)per_part) atomicAdd(&cnt[r4.x], 1);
        if ((unsigned)(r4.y - lo) < (unsigned)per_part) atomicAdd(&cnt[r4.y], 1);
        if ((unsigned)(r4.z - lo) < (unsigned)per_part) atomicAdd(&cnt[r4.z], 1);
        if ((unsigned)(r4.w - lo) < (unsigned)per_part) atomicAdd(&cnt[r4.w], 1);
    }
    if (bp == 0 && chunk == 0) {
        for (int e = (E & ~3) + threadIdx.x; e < E; e += 256)
            atomicAdd(&cnt[adj_row[e]], 1);
    }
}

// ---------------------------------------------------------------------------
// CSR build (2-level scan; nb0 = ceil(N/256) = 196 <= 256)
// ---------------------------------------------------------------------------
__global__ void block_sum_kernel(const int* __restrict__ in,
                                 int* __restrict__ sums, int n) {
    __shared__ int lds[256];
    int i = blockIdx.x * 256 + threadIdx.x;
    lds[threadIdx.x] = (i < n) ? in[i] : 0;
    __syncthreads();
    #pragma unroll
    for (int off = 128; off > 0; off >>= 1) {
        if (threadIdx.x < off) lds[threadIdx.x] += lds[threadIdx.x + off];
        __syncthreads();
    }
    if (threadIdx.x == 0) sums[blockIdx.x] = lds[0];
}

__global__ void scan_sums_kernel(int* __restrict__ sums, int nb,
                                 int* __restrict__ total_out) {
    __shared__ int lds[256];
    int v = (threadIdx.x < nb) ? sums[threadIdx.x] : 0;
    lds[threadIdx.x] = v;
    __syncthreads();
    #pragma unroll
    for (int off = 1; off < 256; off <<= 1) {
        int t = (threadIdx.x >= off) ? lds[threadIdx.x - off] : 0;
        __syncthreads();
        lds[threadIdx.x] += t;
        __syncthreads();
    }
    if (threadIdx.x < nb) sums[threadIdx.x] = lds[threadIdx.x] - v;
    if (threadIdx.x == 255) *total_out = lds[255];
}

__global__ void scan_block_kernel(const int* __restrict__ in,
                                  const int* __restrict__ sums,
                                  int* __restrict__ out1,
                                  int* __restrict__ out2, int n) {
    __shared__ int lds[256];
    int i = blockIdx.x * 256 + threadIdx.x;
    int v = (i < n) ? in[i] : 0;
    lds[threadIdx.x] = v;
    __syncthreads();
    #pragma unroll
    for (int off = 1; off < 256; off <<= 1) {
        int t = (threadIdx.x >= off) ? lds[threadIdx.x - off] : 0;
        __syncthreads();
        lds[threadIdx.x] += t;
        __syncthreads();
    }
    if (i < n) {
        int excl = sums[blockIdx.x] + lds[threadIdx.x] - v;
        out1[i] = excl;
        out2[i] = excl;
    }
}

// ---------------------------------------------------------------------------
// XCD-partitioned permutation build: blocks with blockIdx%8==p only process
// edges whose row is in partition p -> perm/cursor segments single-XCD.
// ---------------------------------------------------------------------------
__global__ void scatter_perm_part_kernel(const int* __restrict__ row,
                                         const int* __restrict__ col,
                                         int* __restrict__ cursor,
                                         int* __restrict__ perm,
                                         int E, int per_part) {
    int bp = blockIdx.x & 7;
    unsigned lo = (unsigned)(bp * per_part);
    int chunk = blockIdx.x >> 3;
    int nchunks = gridDim.x >> 3;
    int E4 = E >> 2;
    for (int i = chunk * 256 + threadIdx.x; i < E4; i += nchunks * 256) {
        int4 r4 = reinterpret_cast<const int4*>(row)[i];
        int e = i << 2;
        if ((unsigned)(r4.x - lo) < (unsigned)per_part) {
            int pos = atomicAdd(&cursor[r4.x], 1);
            perm[pos] = col[e];
        }
        if ((unsigned)(r4.y - lo) < (unsigned)per_part) {
            int pos = atomicAdd(&cursor[r4.y], 1);
            perm[pos] = col[e + 1];
        }
        if ((unsigned)(r4.z - lo) < (unsigned)per_part) {
            int pos = atomicAdd(&cursor[r4.z], 1);
            perm[pos] = col[e + 2];
        }
        if ((unsigned)(r4.w - lo) < (unsigned)per_part) {
            int pos = atomicAdd(&cursor[r4.w], 1);
            perm[pos] = col[e + 3];
        }
    }
    if (bp == 0 && chunk == 0) {
        for (int e = (E & ~3) + threadIdx.x; e < E; e += 256) {
            int pos = atomicAdd(&cursor[row[e]], 1);
            perm[pos] = col[e];
        }
    }
}

// ---------------------------------------------------------------------------
// Dimension-sliced gather with LDS-staged edge lists.
// slice s = blockIdx % 8 (XCD-pinned); block = 64 rows of slice s; 4 lanes
// per row load one uint4 (16B) of the 64B sliced row. The block's 64 rows own
// a CONTIGUOUS perm segment -> stage it into LDS once (coalesced).
// ---------------------------------------------------------------------------
__global__ void gather_sliced_kernel(const int* __restrict__ row_ptr,
                                     const int* __restrict__ perm,
                                     const uint4* __restrict__ src_sl,
                                     uint4* __restrict__ dst_sl,
                                     uint4* __restrict__ dst_cmb_slot,
                                     int N) {
    __shared__ int eidx[ECAP];
    int s = blockIdx.x & (NSL - 1);
    int rb = blockIdx.x >> 3;
    int r0 = rb * 64;
    int rlim = r0 + 64 < N ? r0 + 64 : N;
    int beg0 = row_ptr[r0];
    int end0 = row_ptr[rlim];
    int L = end0 - beg0;
    int Lc = L < ECAP ? L : ECAP;
    for (int i = threadIdx.x; i < Lc; i += 256) eidx[i] = perm[beg0 + i];
    __syncthreads();

    int g = threadIdx.x >> 2;       // row group 0..63
    int j = threadIdx.x & 3;        // uint4 within 64B
    int r = r0 + g;
    if (r >= N) return;             // after __syncthreads: safe

    int beg = row_ptr[r];
    int end = row_ptr[r + 1];
    const uint4* base = src_sl + (size_t)s * N * 4;

    float a0 = 0.f, a1 = 0.f, a2 = 0.f, a3 = 0.f;
    float a4 = 0.f, a5 = 0.f, a6 = 0.f, a7 = 0.f;

    if (end - beg0 <= ECAP) {       // LDS fast path (always, statistically)
        int o = beg - beg0;
        int cnt = end - beg;
        int k = 0;
        for (; k + 3 < cnt; k += 4) {
            int c0 = eidx[o + k];
            int c1 = eidx[o + k + 1];
            int c2 = eidx[o + k + 2];
            int c3 = eidx[o + k + 3];
            uint4 v0 = base[(size_t)c0 * 4 + j];
            uint4 v1 = base[(size_t)c1 * 4 + j];
            uint4 v2 = base[(size_t)c2 * 4 + j];
            uint4 v3 = base[(size_t)c3 * 4 + j];
            ACC8(v0); ACC8(v1); ACC8(v2); ACC8(v3);
        }
        for (; k < cnt; ++k) {
            uint4 v = base[(size_t)eidx[o + k] * 4 + j];
            ACC8(v);
        }
    } else {                        // global fallback (overflow)
        for (int e = beg; e < end; ++e) {
            uint4 v = base[(size_t)perm[e] * 4 + j];
            ACC8(v);
        }
    }

    uint4 o4;
    o4.x = pack2(a0, a1);
    o4.y = pack2(a2, a3);
    o4.z = pack2(a4, a5);
    o4.w = pack2(a6, a7);
    if (dst_sl) dst_sl[((size_t)s * N + r) * 4 + j] = o4;
    dst_cmb_slot[(size_t)r * NODE_U4 + s * 4 + j] = o4;
}

// ---------------------------------------------------------------------------
// Query: 32 lanes per query (uint4 loads), 2 queries per wave (contiguous cmb)
// ---------------------------------------------------------------------------
__global__ void query_kernel(const int* __restrict__ es,
                             const int* __restrict__ et,
                             const uint4* __restrict__ cmb4,
                             const int* __restrict__ row_ptr,
                             float* __restrict__ out, int nq) {
    int gid = blockIdx.x * blockDim.x + threadIdx.x;
    int q = gid >> 5;
    if (q >= nq) return;
    int l = gid & 31;

    int s = es[q];
    int t = et[q];

    const uint4* ns = cmb4 + (size_t)s * NODE_U4;
    const uint4* nt = cmb4 + (size_t)t * NODE_U4;

    uint4 vxs = ns[l];
    uint4 vos = ns[SLOT_OH_U4 + l];
    uint4 vts = ns[SLOT_TH_U4 + l];
    uint4 vxt = nt[l];
    uint4 vot = nt[SLOT_OH_U4 + l];
    uint4 vtt = nt[SLOT_TH_U4 + l];
    float ds = (float)(row_ptr[s + 1] - row_ptr[s]);
    float dt = (float)(row_ptr[t + 1] - row_ptr[t]);

    float c11 = 0.f, c12 = 0.f, c22 = 0.f, cs = 0.f;
    const unsigned int* pxs = (const unsigned int*)&vxs;
    const unsigned int* pxt = (const unsigned int*)&vxt;
    const unsigned int* pos_ = (const unsigned int*)&vos;
    const unsigned int* pot = (const unsigned int*)&vot;
    const unsigned int* pts = (const unsigned int*)&vts;
    const unsigned int* ptt = (const unsigned int*)&vtt;
    #pragma unroll
    for (int k = 0; k < 4; ++k) {
        {
            float fxs = bf_lo(pxs[k]), fxt = bf_lo(pxt[k]);
            float fos = bf_lo(pos_[k]), fot = bf_lo(pot[k]);
            float fts = bf_lo(pts[k]), ftt = bf_lo(ptt[k]);
            c11 += fos * fot;
            c12 += fos * ftt + fts * fot;
            float as = fts - ds * fxs;
            float bt = ftt - dt * fxt;
            c22 += as * bt;
            cs  += fos * fts + fot * ftt;
        }
        {
            float fxs = bf_hi(pxs[k]), fxt = bf_hi(pxt[k]);
            float fos = bf_hi(pos_[k]), fot = bf_hi(pot[k]);
            float fts = bf_hi(pts[k]), ftt = bf_hi(ptt[k]);
            c11 += fos * fot;
            c12 += fos * ftt + fts * fot;
            float as = fts - ds * fxs;
            float bt = ftt - dt * fxt;
            c22 += as * bt;
            cs  += fos * fts + fot * ftt;
        }
    }

    #pragma unroll
    for (int off = 16; off > 0; off >>= 1) {
        c11 += __shfl_xor(c11, off);
        c12 += __shfl_xor(c12, off);
        c22 += __shfl_xor(c22, off);
        cs  += __shfl_xor(cs,  off);
    }

    if (l == 0) {
        out[q]          = c11;
        out[nq + q]     = c12;
        out[2 * nq + q] = c22;
        out[3 * nq + q] = cs;
    }
}

// ---------------------------------------------------------------------------
extern "C" void kernel_launch(void* const* d_in, const int* in_sizes, int n_in,
                              void* d_out, int out_size, void* d_ws, size_t ws_size,
                              hipStream_t stream) {
    const int*   edges        = (const int*)  d_in[0];  // [2, EQ]
    const int*   adj_row      = (const int*)  d_in[1];  // [E]
    const int*   adj_col      = (const int*)  d_in[2];  // [E]
    const float* node_weight  = (const float*)d_in[3];  // [N]
    const float* node_vectors = (const float*)d_in[4];  // [N, DIM]

    const int EQ = in_sizes[0] / 2;
    const int E  = in_sizes[1];
    const int N  = in_sizes[3];

    // workspace layout
    uint2* cmb   = (uint2*)d_ws;                        // 76.8 MB contiguous
    uint2* xs_sl = cmb + (size_t)N * NODE_U2;           // 25.6 MB sliced x
    uint2* oh_sl = xs_sl + (size_t)N * NSL * 8;         // 25.6 MB sliced oh
    int* row_ptr = (int*)(oh_sl + (size_t)N * NSL * 8); // [N+1]
    int* cursor  = row_ptr + (N + 1);                   // [N]
    int* cnt     = cursor + N;                          // [N]
    int* perm    = cnt + N;                             // [E]
    int* s1      = perm + E;                            // [ceil(N/256)]

    const int* es = edges;
    const int* et = edges + EQ;
    float* out = (float*)d_out;

    const int nb0 = (N + 255) / 256;   // 196
    const int per_part = (N + 7) / 8;  // 6250

    // --- fused x (both layouts) + partitioned histogram ---
    hipMemsetAsync(cnt, 0, (size_t)N * sizeof(int), stream);
    int total_u2 = N * 64;
    x_and_hist_kernel<<<2048, 256, 0, stream>>>(node_vectors, node_weight,
                                                cmb, xs_sl, total_u2, N,
                                                adj_row, cnt, E, per_part);

    // --- CSR scan + partitioned permutation ---
    block_sum_kernel<<<nb0, 256, 0, stream>>>(cnt, s1, N);
    scan_sums_kernel<<<1, 256, 0, stream>>>(s1, nb0, row_ptr + N);
    scan_block_kernel<<<nb0, 256, 0, stream>>>(cnt, s1, row_ptr, cursor, N);
    scatter_perm_part_kernel<<<2048, 256, 0, stream>>>(adj_row, adj_col,
                                                       cursor, perm, E,
                                                       per_part);

    // --- one_hop / two_hop via XCD-pinned sliced gather (LDS edge stage) ---
    const uint4* xs4 = (const uint4*)xs_sl;
    uint4* oh4 = (uint4*)oh_sl;
    uint4* cmb4 = (uint4*)cmb;
    int nrb = (N + 63) / 64;           // 782 row-blocks
    int gblocks = nrb * NSL;           // 6256
    gather_sliced_kernel<<<gblocks, 256, 0, stream>>>(
        row_ptr, perm, xs4, oh4, cmb4 + SLOT_OH_U4, N);
    gather_sliced_kernel<<<gblocks, 256, 0, stream>>>(
        row_ptr, perm, (const uint4*)oh4, (uint4*)nullptr,
        cmb4 + SLOT_TH_U4, N);

    // --- queries ---
    int qthreads = EQ * 32;
    query_kernel<<<(qthreads + 255) / 256, 256, 0, stream>>>(
        es, et, cmb4, row_ptr, out, EQ);
}